// Round 1
// baseline (27945.361 us; speedup 1.0000x reference)
//
#include <hip/hip_runtime.h>

// ---------------------------------------------------------------------------
// 2-layer LSTM LM, S=512 B=512 H=256 V=128.
// Round 0: correctness-first fp32 persistent kernel, batch-partitioned
// (no cross-workgroup sync needed: recurrence independent per batch row).
// 128 blocks x 512 threads; block owns 4 batch rows for all 512 steps.
// Weights pre-transposed to [k][col][gate] so a thread owning h-column `col`
// loads one float4 per k per matrix (lane-consecutive -> coalesced) and the
// i,f,g,o gates arrive together. h double-buffered in LDS; c stays in regs.
// Output projection fused per step (writes d_out directly, no h1 history).
// ---------------------------------------------------------------------------

#define S_ 512
#define B_ 512
#define H_ 256
#define V_ 128

// ws layout (float offsets). Total 822272 floats = 3.3 MB.
#define OFF_W0   0         // [256][256][4]  from w_hh0:  W0p[k][col][gate] = w_hh0[gate*H+col][k]
#define OFF_W1I  262144    // same from w_ih1
#define OFF_W1H  524288    // same from w_hh1
#define OFF_WO   786432    // [256][128]     WOp[k][v] = W_out[v][k]
#define OFF_WX   819200    // [256][4]       w_ih0 regrouped per (col,gate)
#define OFF_BZ0  820224    // [256][4]       b_ih0+b_hh0
#define OFF_BZ1  821248    // [256][4]       b_ih1+b_hh1

__device__ __forceinline__ float sigm(float z) {
  return 1.0f / (1.0f + __expf(-z));
}
__device__ __forceinline__ float tanh_fast(float z) {
  // 2/(1+e^{-2z}) - 1 ; saturates cleanly via inf for large |z|
  return 2.0f / (1.0f + __expf(-2.0f * z)) - 1.0f;
}

__global__ void prep_kernel(const float* __restrict__ w_ih0, const float* __restrict__ w_hh0,
                            const float* __restrict__ b_ih0, const float* __restrict__ b_hh0,
                            const float* __restrict__ w_ih1, const float* __restrict__ w_hh1,
                            const float* __restrict__ b_ih1, const float* __restrict__ b_hh1,
                            const float* __restrict__ W_out, float* __restrict__ ws) {
  int idx = blockIdx.x * blockDim.x + threadIdx.x;
  if (idx < 262144) {
    int k    = idx >> 10;       // 0..255
    int rem  = idx & 1023;
    int col  = rem >> 2;        // 0..255
    int gate = rem & 3;         // i,f,g,o
    int src  = (gate * H_ + col) * H_ + k;   // w[G][k], G = gate*H + col
    ws[OFF_W0  + idx] = w_hh0[src];
    ws[OFF_W1I + idx] = w_ih1[src];
    ws[OFF_W1H + idx] = w_hh1[src];
  }
  if (idx < 32768) {
    int k = idx >> 7, v = idx & 127;
    ws[OFF_WO + idx] = W_out[v * H_ + k];
  }
  if (idx < 1024) {
    int col = idx >> 2, gate = idx & 3;
    int g = gate * H_ + col;
    ws[OFF_WX  + idx] = w_ih0[g];            // w_ih0 is [4H][1]
    ws[OFF_BZ0 + idx] = b_ih0[g] + b_hh0[g];
    ws[OFF_BZ1 + idx] = b_ih1[g] + b_hh1[g];
  }
}

__global__ __launch_bounds__(512) void lstm_fused(const int* __restrict__ x,
                                                  const float* __restrict__ ws,
                                                  const float* __restrict__ b_out,
                                                  float* __restrict__ out) {
  // double-buffered h for both layers; 16 KB LDS
  __shared__ __align__(16) float h0s[2][4][H_];
  __shared__ __align__(16) float h1s[2][4][H_];

  const int tid  = threadIdx.x;
  const int col  = tid & 255;     // h-column this thread owns
  const int half = tid >> 8;      // 0/1 -> which pair of batch rows
  const int bloc = half * 2;      // local batch base (0 or 2)
  const int b0   = blockIdx.x * 4;

  const float4* __restrict__ W0  = (const float4*)(ws + OFF_W0);
  const float4* __restrict__ W1i = (const float4*)(ws + OFF_W1I);
  const float4* __restrict__ W1h = (const float4*)(ws + OFF_W1H);
  const float*  __restrict__ WO  = ws + OFF_WO;
  const float4 wx  = ((const float4*)(ws + OFF_WX))[col];
  const float4 bz0 = ((const float4*)(ws + OFF_BZ0))[col];
  const float4 bz1 = ((const float4*)(ws + OFF_BZ1))[col];

  // projection mapping: thread -> (pb, pv); uniform pb per wave
  const int pb = tid >> 7;        // 0..3
  const int pv = tid & 127;       // 0..127
  const float bo = b_out[pv];

  // cell states stay in registers (exact fp32; c can grow when f~1)
  float c0A = 0.f, c0B = 0.f, c1A = 0.f, c1B = 0.f;

  for (int i = tid; i < 2 * 4 * H_; i += 512) {
    (&h0s[0][0][0])[i] = 0.f;
    (&h1s[0][0][0])[i] = 0.f;
  }
  __syncthreads();

  int p = 0;
  #pragma unroll 1
  for (int t = 0; t < S_; ++t) {
    const float xvA = (float)x[t * B_ + b0 + bloc + 0];
    const float xvB = (float)x[t * B_ + b0 + bloc + 1];

    // ------------------ layer 0: h0 @ w_hh0^T ------------------
    float aA0 = 0.f, aA1 = 0.f, aA2 = 0.f, aA3 = 0.f;
    float aB0 = 0.f, aB1 = 0.f, aB2 = 0.f, aB3 = 0.f;
    {
      const float* hA = h0s[p][bloc + 0];
      const float* hB = h0s[p][bloc + 1];
      #pragma unroll 2
      for (int k = 0; k < H_; k += 4) {
        float4 ha = *(const float4*)(hA + k);
        float4 hb = *(const float4*)(hB + k);
        float4 w0 = W0[(k + 0) * 256 + col];
        float4 w1 = W0[(k + 1) * 256 + col];
        float4 w2 = W0[(k + 2) * 256 + col];
        float4 w3 = W0[(k + 3) * 256 + col];
        aA0 += ha.x * w0.x + ha.y * w1.x + ha.z * w2.x + ha.w * w3.x;
        aA1 += ha.x * w0.y + ha.y * w1.y + ha.z * w2.y + ha.w * w3.y;
        aA2 += ha.x * w0.z + ha.y * w1.z + ha.z * w2.z + ha.w * w3.z;
        aA3 += ha.x * w0.w + ha.y * w1.w + ha.z * w2.w + ha.w * w3.w;
        aB0 += hb.x * w0.x + hb.y * w1.x + hb.z * w2.x + hb.w * w3.x;
        aB1 += hb.x * w0.y + hb.y * w1.y + hb.z * w2.y + hb.w * w3.y;
        aB2 += hb.x * w0.z + hb.y * w1.z + hb.z * w2.z + hb.w * w3.z;
        aB3 += hb.x * w0.w + hb.y * w1.w + hb.z * w2.w + hb.w * w3.w;
      }
    }
    {
      float iA = aA0 + xvA * wx.x + bz0.x;
      float fA = aA1 + xvA * wx.y + bz0.y;
      float gA = aA2 + xvA * wx.z + bz0.z;
      float oA = aA3 + xvA * wx.w + bz0.w;
      c0A = sigm(fA) * c0A + sigm(iA) * tanh_fast(gA);
      float h0nA = sigm(oA) * tanh_fast(c0A);

      float iB = aB0 + xvB * wx.x + bz0.x;
      float fB = aB1 + xvB * wx.y + bz0.y;
      float gB = aB2 + xvB * wx.z + bz0.z;
      float oB = aB3 + xvB * wx.w + bz0.w;
      c0B = sigm(fB) * c0B + sigm(iB) * tanh_fast(gB);
      float h0nB = sigm(oB) * tanh_fast(c0B);

      h0s[p ^ 1][bloc + 0][col] = h0nA;
      h0s[p ^ 1][bloc + 1][col] = h0nB;
    }
    __syncthreads();

    // ------------------ layer 1: h0_new @ w_ih1^T + h1 @ w_hh1^T ------------------
    float dA0 = 0.f, dA1 = 0.f, dA2 = 0.f, dA3 = 0.f;
    float dB0 = 0.f, dB1 = 0.f, dB2 = 0.f, dB3 = 0.f;
    {
      const float* hA0 = h0s[p ^ 1][bloc + 0];
      const float* hB0 = h0s[p ^ 1][bloc + 1];
      const float* hA1 = h1s[p][bloc + 0];
      const float* hB1 = h1s[p][bloc + 1];
      #pragma unroll 2
      for (int k = 0; k < H_; k += 4) {
        {
          float4 ha = *(const float4*)(hA0 + k);
          float4 hb = *(const float4*)(hB0 + k);
          float4 w0 = W1i[(k + 0) * 256 + col];
          float4 w1 = W1i[(k + 1) * 256 + col];
          float4 w2 = W1i[(k + 2) * 256 + col];
          float4 w3 = W1i[(k + 3) * 256 + col];
          dA0 += ha.x * w0.x + ha.y * w1.x + ha.z * w2.x + ha.w * w3.x;
          dA1 += ha.x * w0.y + ha.y * w1.y + ha.z * w2.y + ha.w * w3.y;
          dA2 += ha.x * w0.z + ha.y * w1.z + ha.z * w2.z + ha.w * w3.z;
          dA3 += ha.x * w0.w + ha.y * w1.w + ha.z * w2.w + ha.w * w3.w;
          dB0 += hb.x * w0.x + hb.y * w1.x + hb.z * w2.x + hb.w * w3.x;
          dB1 += hb.x * w0.y + hb.y * w1.y + hb.z * w2.y + hb.w * w3.y;
          dB2 += hb.x * w0.z + hb.y * w1.z + hb.z * w2.z + hb.w * w3.z;
          dB3 += hb.x * w0.w + hb.y * w1.w + hb.z * w2.w + hb.w * w3.w;
        }
        {
          float4 ha = *(const float4*)(hA1 + k);
          float4 hb = *(const float4*)(hB1 + k);
          float4 w0 = W1h[(k + 0) * 256 + col];
          float4 w1 = W1h[(k + 1) * 256 + col];
          float4 w2 = W1h[(k + 2) * 256 + col];
          float4 w3 = W1h[(k + 3) * 256 + col];
          dA0 += ha.x * w0.x + ha.y * w1.x + ha.z * w2.x + ha.w * w3.x;
          dA1 += ha.x * w0.y + ha.y * w1.y + ha.z * w2.y + ha.w * w3.y;
          dA2 += ha.x * w0.z + ha.y * w1.z + ha.z * w2.z + ha.w * w3.z;
          dA3 += ha.x * w0.w + ha.y * w1.w + ha.z * w2.w + ha.w * w3.w;
          dB0 += hb.x * w0.x + hb.y * w1.x + hb.z * w2.x + hb.w * w3.x;
          dB1 += hb.x * w0.y + hb.y * w1.y + hb.z * w2.y + hb.w * w3.y;
          dB2 += hb.x * w0.z + hb.y * w1.z + hb.z * w2.z + hb.w * w3.z;
          dB3 += hb.x * w0.w + hb.y * w1.w + hb.z * w2.w + hb.w * w3.w;
        }
      }
    }
    {
      float iA = dA0 + bz1.x;
      float fA = dA1 + bz1.y;
      float gA = dA2 + bz1.z;
      float oA = dA3 + bz1.w;
      c1A = sigm(fA) * c1A + sigm(iA) * tanh_fast(gA);
      float h1nA = sigm(oA) * tanh_fast(c1A);

      float iB = dB0 + bz1.x;
      float fB = dB1 + bz1.y;
      float gB = dB2 + bz1.z;
      float oB = dB3 + bz1.w;
      c1B = sigm(fB) * c1B + sigm(iB) * tanh_fast(gB);
      float h1nB = sigm(oB) * tanh_fast(c1B);

      h1s[p ^ 1][bloc + 0][col] = h1nA;
      h1s[p ^ 1][bloc + 1][col] = h1nB;
    }
    __syncthreads();

    // ------------------ fused output projection: out[t] = h1_t @ W_out^T + b_out ---
    {
      float acc = 0.f;
      const float* hp = h1s[p ^ 1][pb];
      #pragma unroll 2
      for (int k = 0; k < H_; k += 4) {
        float4 hv = *(const float4*)(hp + k);
        acc += hv.x * WO[(k + 0) * V_ + pv];
        acc += hv.y * WO[(k + 1) * V_ + pv];
        acc += hv.z * WO[(k + 2) * V_ + pv];
        acc += hv.w * WO[(k + 3) * V_ + pv];
      }
      out[(size_t)(t * B_ + b0 + pb) * V_ + pv] = acc + bo;
    }

    p ^= 1;
  }
}

extern "C" void kernel_launch(void* const* d_in, const int* in_sizes, int n_in,
                              void* d_out, int out_size, void* d_ws, size_t ws_size,
                              hipStream_t stream) {
  const int*   x     = (const int*)d_in[0];
  const float* w_ih0 = (const float*)d_in[1];
  const float* w_hh0 = (const float*)d_in[2];
  const float* b_ih0 = (const float*)d_in[3];
  const float* b_hh0 = (const float*)d_in[4];
  const float* w_ih1 = (const float*)d_in[5];
  const float* w_hh1 = (const float*)d_in[6];
  const float* b_ih1 = (const float*)d_in[7];
  const float* b_hh1 = (const float*)d_in[8];
  const float* W_out = (const float*)d_in[9];
  const float* b_out = (const float*)d_in[10];
  float* ws  = (float*)d_ws;
  float* out = (float*)d_out;

  prep_kernel<<<1024, 256, 0, stream>>>(w_ih0, w_hh0, b_ih0, b_hh0,
                                        w_ih1, w_hh1, b_ih1, b_hh1, W_out, ws);
  lstm_fused<<<128, 512, 0, stream>>>(x, ws, b_out, out);
}

// Round 2
// 13257.715 us; speedup vs baseline: 2.1079x; 2.1079x over previous
//
#include <hip/hip_runtime.h>

// ---------------------------------------------------------------------------
// 2-layer LSTM LM, S=512 B=512 H=256 V=128 — Round 1.
// bf16 weights + MFMA 16x16x32, batch-partitioned: 32 blocks x 512 threads,
// each block owns 16 batch rows for all 512 steps (no cross-block sync).
// Weights pre-packed by prep kernel into per-wave MFMA B-fragment streams
// (contiguous 16B/lane dwordx4 loads straight from L2 -> VGPR -> MFMA).
// h kept effectively fp32 via hi/lo bf16 split (2 MFMAs per B fragment).
// h tiles in LDS, XOR-swizzled; c state in registers; fused projection.
// Per-CU ingest: 1.65 MB/step bf16 -> ~10-15 us/step (per-CU L2 BW bound).
// ---------------------------------------------------------------------------

#define S_ 512
#define B_ 512
#define H_ 256
#define V_ 128

typedef __attribute__((ext_vector_type(8))) short bf16x8;
typedef __attribute__((ext_vector_type(4))) float f32x4;
typedef __attribute__((ext_vector_type(8))) ushort ushort8;

// bf16 element offsets in ws
#define OFF_B0   0         // [w8][kk8][j8][lane64][8]  = 262144 bf16 (w_hh0)
#define OFF_B1   262144    // [w8][kk16][j8][lane64][8] = 524288 bf16 (w_ih1|w_hh1)
#define OFF_BP   786432    // [w8][kk8][lane64][8]      = 32768 bf16 (W_out)
// fp32 offsets (region starts at byte 1638400 = float 409600)
#define OFF_WX   409600    // [1024] w_ih0
#define OFF_BZ0  410624    // [1024] b_ih0+b_hh0
#define OFF_BZ1  411648    // [1024] b_ih1+b_hh1

__device__ __forceinline__ ushort f2bf(float f) {
  union { float f; unsigned u; } v; v.f = f;
  unsigned r = (v.u + 0x7fff + ((v.u >> 16) & 1)) >> 16;   // RNE
  return (ushort)r;
}
__device__ __forceinline__ float bf2f(ushort h) {
  union { unsigned u; float f; } v; v.u = ((unsigned)h) << 16;
  return v.f;
}
__device__ __forceinline__ float sigm(float z) { return 1.0f / (1.0f + __expf(-z)); }
__device__ __forceinline__ float tanh_fast(float z) {
  return 2.0f / (1.0f + __expf(-2.0f * z)) - 1.0f;
}

// ---------------------------------------------------------------------------
// prep: pack weights into per-wave MFMA B-fragment streams (bf16).
// B frag (16x16x32): lane l, elem i -> B[k][n], k = kk*32 + (l>>4)*8 + i,
// n = n0 + (l&15). Gate tile order per wave w: j = gate*2+half,
// n0 = (j>>1)*256 + w*32 + (j&1)*16.
// ---------------------------------------------------------------------------
__global__ void prep_kernel(const float* __restrict__ w_ih0, const float* __restrict__ w_hh0,
                            const float* __restrict__ b_ih0, const float* __restrict__ b_hh0,
                            const float* __restrict__ w_ih1, const float* __restrict__ w_hh1,
                            const float* __restrict__ b_ih1, const float* __restrict__ b_hh1,
                            const float* __restrict__ W_out, void* __restrict__ ws) {
  ushort* wsb = (ushort*)ws;
  float*  wsf = (float*)ws;
  int idx = blockIdx.x * blockDim.x + threadIdx.x;

  const float* src = nullptr;
  int dst = -1;
  if (idx < 32768) {                       // B0: w_hh0
    int lane = idx & 63, j = (idx >> 6) & 7, kk = (idx >> 9) & 7, w = idx >> 12;
    int n  = ((j >> 1) << 8) + w * 32 + ((j & 1) << 4) + (lane & 15);
    int k0 = kk * 32 + (lane >> 4) * 8;
    src = w_hh0 + n * H_ + k0;
    dst = OFF_B0 + idx * 8;
  } else if (idx < 32768 + 65536) {        // B1: w_ih1 (k<256) | w_hh1
    int t = idx - 32768;
    int lane = t & 63, j = (t >> 6) & 7, kk = (t >> 9) & 15, w = t >> 13;
    int n  = ((j >> 1) << 8) + w * 32 + ((j & 1) << 4) + (lane & 15);
    int k0 = kk * 32 + (lane >> 4) * 8;
    src = (k0 < H_) ? (w_ih1 + n * H_ + k0) : (w_hh1 + n * H_ + (k0 - H_));
    dst = OFF_B1 + t * 8;
  } else if (idx < 32768 + 65536 + 4096) { // BP: W_out
    int t = idx - (32768 + 65536);
    int lane = t & 63, kk = (t >> 6) & 7, w = t >> 9;
    int n  = w * 16 + (lane & 15);
    int k0 = kk * 32 + (lane >> 4) * 8;
    src = W_out + n * H_ + k0;
    dst = OFF_BP + t * 8;
  } else if (idx < 32768 + 65536 + 4096 + 1024) {  // scalars
    int t = idx - (32768 + 65536 + 4096);
    wsf[OFF_WX  + t] = w_ih0[t];
    wsf[OFF_BZ0 + t] = b_ih0[t] + b_hh0[t];
    wsf[OFF_BZ1 + t] = b_ih1[t] + b_hh1[t];
    return;
  } else {
    return;
  }
  ushort8 v;
  #pragma unroll
  for (int i = 0; i < 8; ++i) v[i] = f2bf(src[i]);
  *(ushort8*)(wsb + dst) = v;
}

// A-fragment read from swizzled LDS h tile [16 rows][256 k] bf16.
// lane l: row = l&15, k = kk*32 + (l>>4)*8 + i. XOR swizzle on byte bits 4-6.
__device__ __forceinline__ bf16x8 ldsA(const ushort* base, int lane, int kk) {
  int row  = lane & 15;
  int byte = row * 512 + kk * 64 + ((lane >> 4) << 4);
  byte ^= (row & 7) << 4;
  return *(const bf16x8*)((const char*)base + byte);
}
__device__ __forceinline__ void ldsW(ushort* base, int row, int col, ushort v) {
  int byte = row * 512 + col * 2;
  byte ^= (row & 7) << 4;
  *(ushort*)((char*)base + byte) = v;
}

__global__ __launch_bounds__(512, 2) void lstm_mfma(const int* __restrict__ x,
                                                    const void* __restrict__ ws,
                                                    const float* __restrict__ b_out,
                                                    float* __restrict__ out) {
  const ushort* wsb = (const ushort*)ws;
  const float*  wsf = (const float*)ws;

  __shared__ __align__(16) ushort HH[4][4096];  // H0h, H0l, H1h, H1l (32 KB)
  ushort* H0h = HH[0]; ushort* H0l = HH[1];
  ushort* H1h = HH[2]; ushort* H1l = HH[3];

  const int tid  = threadIdx.x;
  const int lane = tid & 63;
  const int w    = tid >> 6;          // wave 0..7
  const int b0   = blockIdx.x * 16;   // batch base (32 blocks x 16 rows)
  const int grp  = lane >> 4;         // 0..3 (row group)
  const int l15  = lane & 15;

  // per-wave B streams
  const ushort* B0w = wsb + OFF_B0 + (size_t)w * 32768;
  const ushort* B1w = wsb + OFF_B1 + (size_t)w * 65536;
  const ushort* BPw = wsb + OFF_BP + (size_t)w * 4096;

  // per-lane scalar preloads: this lane's 2 h-cols (half 0/1) x 4 gates
  float wxv[4][2], bz0v[4][2], bz1v[4][2];
  const int colA = w * 32 + l15;
  #pragma unroll
  for (int g = 0; g < 4; ++g) {
    #pragma unroll
    for (int hf = 0; hf < 2; ++hf) {
      int col = colA + hf * 16;
      wxv[g][hf]  = wsf[OFF_WX  + g * H_ + col];
      bz0v[g][hf] = wsf[OFF_BZ0 + g * H_ + col];
      bz1v[g][hf] = wsf[OFF_BZ1 + g * H_ + col];
    }
  }
  const float bo = b_out[w * 16 + l15];

  float c0s[8], c1s[8];
  #pragma unroll
  for (int i = 0; i < 8; ++i) { c0s[i] = 0.f; c1s[i] = 0.f; }

  for (int i = tid; i < 4 * 4096; i += 512) (&HH[0][0])[i] = 0;
  __syncthreads();

  #pragma unroll 1
  for (int t = 0; t < S_; ++t) {
    // x values for this lane's 4 batch rows (broadcast within 16-lane group)
    const int4 xq = *(const int4*)(x + t * B_ + b0 + grp * 4);
    float xvf[4] = {(float)xq.x, (float)xq.y, (float)xq.z, (float)xq.w};

    // ---------------- layer 0: gates0 = [h0_hi + h0_lo] @ w_hh0^T ----------
    f32x4 acc[8];
    #pragma unroll
    for (int j = 0; j < 8; ++j) acc[j] = (f32x4){0.f, 0.f, 0.f, 0.f};
    #pragma unroll 2
    for (int kk = 0; kk < 8; ++kk) {
      bf16x8 ah = ldsA(H0h, lane, kk);
      bf16x8 al = ldsA(H0l, lane, kk);
      #pragma unroll
      for (int j = 0; j < 8; ++j) {
        bf16x8 b = *(const bf16x8*)(B0w + ((kk * 8 + j) * 64 + lane) * 8);
        acc[j] = __builtin_amdgcn_mfma_f32_16x16x32_bf16(ah, b, acc[j], 0, 0, 0);
        acc[j] = __builtin_amdgcn_mfma_f32_16x16x32_bf16(al, b, acc[j], 0, 0, 0);
      }
    }
    __syncthreads();

    // epilogue 0: nonlinearity, write h0_new (hi/lo) into H0
    #pragma unroll
    for (int hf = 0; hf < 2; ++hf) {
      const int col = colA + hf * 16;
      #pragma unroll
      for (int r = 0; r < 4; ++r) {
        float vi = acc[0 + hf][r] + xvf[r] * wxv[0][hf] + bz0v[0][hf];
        float vf = acc[2 + hf][r] + xvf[r] * wxv[1][hf] + bz0v[1][hf];
        float vg = acc[4 + hf][r] + xvf[r] * wxv[2][hf] + bz0v[2][hf];
        float vo = acc[6 + hf][r] + xvf[r] * wxv[3][hf] + bz0v[3][hf];
        float c  = sigm(vf) * c0s[hf * 4 + r] + sigm(vi) * tanh_fast(vg);
        c0s[hf * 4 + r] = c;
        float h  = sigm(vo) * tanh_fast(c);
        ushort hi = f2bf(h);
        ushort lo = f2bf(h - bf2f(hi));
        int row = grp * 4 + r;
        ldsW(H0h, row, col, hi);
        ldsW(H0l, row, col, lo);
      }
    }
    __syncthreads();

    // ---------------- layer 1: gates1 = h0_new @ w_ih1^T + h1 @ w_hh1^T ----
    f32x4 acc1[8];
    #pragma unroll
    for (int j = 0; j < 8; ++j) acc1[j] = (f32x4){0.f, 0.f, 0.f, 0.f};
    #pragma unroll 2
    for (int kk = 0; kk < 8; ++kk) {           // K 0..255: A = h0_new
      bf16x8 ah = ldsA(H0h, lane, kk);
      bf16x8 al = ldsA(H0l, lane, kk);
      #pragma unroll
      for (int j = 0; j < 8; ++j) {
        bf16x8 b = *(const bf16x8*)(B1w + ((kk * 8 + j) * 64 + lane) * 8);
        acc1[j] = __builtin_amdgcn_mfma_f32_16x16x32_bf16(ah, b, acc1[j], 0, 0, 0);
        acc1[j] = __builtin_amdgcn_mfma_f32_16x16x32_bf16(al, b, acc1[j], 0, 0, 0);
      }
    }
    #pragma unroll 2
    for (int kk = 8; kk < 16; ++kk) {          // K 256..511: A = h1_old
      bf16x8 ah = ldsA(H1h, lane, kk & 7);
      bf16x8 al = ldsA(H1l, lane, kk & 7);
      #pragma unroll
      for (int j = 0; j < 8; ++j) {
        bf16x8 b = *(const bf16x8*)(B1w + ((kk * 8 + j) * 64 + lane) * 8);
        acc1[j] = __builtin_amdgcn_mfma_f32_16x16x32_bf16(ah, b, acc1[j], 0, 0, 0);
        acc1[j] = __builtin_amdgcn_mfma_f32_16x16x32_bf16(al, b, acc1[j], 0, 0, 0);
      }
    }
    __syncthreads();

    // epilogue 1: write h1_new (hi/lo) into H1
    #pragma unroll
    for (int hf = 0; hf < 2; ++hf) {
      const int col = colA + hf * 16;
      #pragma unroll
      for (int r = 0; r < 4; ++r) {
        float vi = acc1[0 + hf][r] + bz1v[0][hf];
        float vf = acc1[2 + hf][r] + bz1v[1][hf];
        float vg = acc1[4 + hf][r] + bz1v[2][hf];
        float vo = acc1[6 + hf][r] + bz1v[3][hf];
        float c  = sigm(vf) * c1s[hf * 4 + r] + sigm(vi) * tanh_fast(vg);
        c1s[hf * 4 + r] = c;
        float h  = sigm(vo) * tanh_fast(c);
        ushort hi = f2bf(h);
        ushort lo = f2bf(h - bf2f(hi));
        int row = grp * 4 + r;
        ldsW(H1h, row, col, hi);
        ldsW(H1l, row, col, lo);
      }
    }
    __syncthreads();

    // ---------------- fused projection: out[t] = h1_new @ W_out^T + b_out --
    f32x4 ap = (f32x4){0.f, 0.f, 0.f, 0.f};
    #pragma unroll 2
    for (int kk = 0; kk < 8; ++kk) {
      bf16x8 ah = ldsA(H1h, lane, kk);
      bf16x8 al = ldsA(H1l, lane, kk);
      bf16x8 b  = *(const bf16x8*)(BPw + (kk * 64 + lane) * 8);
      ap = __builtin_amdgcn_mfma_f32_16x16x32_bf16(ah, b, ap, 0, 0, 0);
      ap = __builtin_amdgcn_mfma_f32_16x16x32_bf16(al, b, ap, 0, 0, 0);
    }
    {
      const int v = w * 16 + l15;
      #pragma unroll
      for (int r = 0; r < 4; ++r) {
        int row = grp * 4 + r;
        out[((size_t)(t * B_ + b0 + row)) * V_ + v] = ap[r] + bo;
      }
    }
    // no barrier needed here: next layer0 reads H0 (stable since epilogue 0);
    // proj reads H1 which is rewritten only after two more barriers.
  }
}

extern "C" void kernel_launch(void* const* d_in, const int* in_sizes, int n_in,
                              void* d_out, int out_size, void* d_ws, size_t ws_size,
                              hipStream_t stream) {
  const int*   x     = (const int*)d_in[0];
  const float* w_ih0 = (const float*)d_in[1];
  const float* w_hh0 = (const float*)d_in[2];
  const float* b_ih0 = (const float*)d_in[3];
  const float* b_hh0 = (const float*)d_in[4];
  const float* w_ih1 = (const float*)d_in[5];
  const float* w_hh1 = (const float*)d_in[6];
  const float* b_ih1 = (const float*)d_in[7];
  const float* b_hh1 = (const float*)d_in[8];
  const float* W_out = (const float*)d_in[9];
  const float* b_out = (const float*)d_in[10];

  prep_kernel<<<404, 256, 0, stream>>>(w_ih0, w_hh0, b_ih0, b_hh0,
                                       w_ih1, w_hh1, b_ih1, b_hh1, W_out, d_ws);
  lstm_mfma<<<32, 512, 0, stream>>>(x, d_ws, b_out, (float*)d_out);
}

// Round 4
// 7750.863 us; speedup vs baseline: 3.6055x; 1.7105x over previous
//
#include <hip/hip_runtime.h>

// ---------------------------------------------------------------------------
// 2-layer LSTM LM, S=512 B=512 H=256 V=128 — Round 3: weight-stationary,
// race-hardened. 256 blocks = 32 batch-groups x 8 col-blocks; weights live in
// VGPRs as fp16 MFMA B-fragments. Per step, groups all-gather h0/h1 (fp32)
// via agent-scope atomics; publish is ordered by explicit per-wave
// s_waitcnt vmcnt(0) + RELEASE counter add; readers ACQUIRE-spin.
// h precision: fp16 hi/lo split (~fp32 exact) built at LDS staging time;
// c state fp32 in registers. Projection + layer1(h1-half) scheduled before
// the h0 gather to shorten the per-step critical path.
// ---------------------------------------------------------------------------

#define S_ 512
#define B_ 512
#define H_ 256
#define V_ 128

typedef _Float16 f16;
typedef __attribute__((ext_vector_type(8))) _Float16 f16x8;
typedef __attribute__((ext_vector_type(4))) float f32x4;
typedef unsigned long long u64;

// ws BYTE offsets
#define OFF_B0   0          // f16 frags [j8][w8][kk8][64][8]  = 512 KB (w_hh0)
#define OFF_B1   524288     // f16 frags [j8][w8][kk16][64][8] = 1 MB  (w_ih1|w_hh1)
#define OFF_BP   1572864    // f16 frags [j8][w8][64][8]       = 64 KB (W_out)
#define OFF_H0X  1638400    // fp32 [g32][16][256] = 512 KB (h0 exchange)
#define OFF_H1X  2162688    // fp32 [g32][16][256] = 512 KB (h1 exchange)
#define OFF_CNT  2686976    // [g32][32 u32] = 4 KB (cnt0 at +0, cnt1 at +64B)

__device__ __forceinline__ float sigm(float z) { return 1.0f / (1.0f + __expf(-z)); }
__device__ __forceinline__ float tanh_fast(float z) {
  return 2.0f / (1.0f + __expf(-2.0f * z)) - 1.0f;
}

// ---------------------------------------------------------------------------
// prep: pack weights to fp16 MFMA B-fragment streams; zero exchange+counters.
// B frag (16x16x32): lane l elem i -> B[k][n], k = kk*32+(l>>4)*8+i, n = l&15.
// Wave w of block j: gate = w>>1, half = w&1, hcol = j*32+half*16+n.
// ---------------------------------------------------------------------------
__global__ void prep_kernel(const float* __restrict__ w_hh0,
                            const float* __restrict__ w_ih1, const float* __restrict__ w_hh1,
                            const float* __restrict__ W_out, void* __restrict__ ws) {
  int idx = blockIdx.x * blockDim.x + threadIdx.x;
  f16* wsh = (f16*)ws;
  if (idx < 32768) {                                  // B0 (w_hh0)
    int j = idx >> 12, w = (idx >> 9) & 7, kk = (idx >> 6) & 7, lane = idx & 63;
    int gate = w >> 1, half = w & 1;
    int hcol = j * 32 + half * 16 + (lane & 15);
    int G = gate * H_ + hcol;
    int k0 = kk * 32 + (lane >> 4) * 8;
    f16x8 v;
    #pragma unroll
    for (int i = 0; i < 8; ++i) v[i] = (f16)w_hh0[G * H_ + k0 + i];
    *(f16x8*)(wsh + idx * 8) = v;
  } else if (idx < 32768 + 65536) {                   // B1 (K=512: w_ih1 | w_hh1)
    int t = idx - 32768;
    int j = t >> 13, w = (t >> 10) & 7, kk = (t >> 6) & 15, lane = t & 63;
    int gate = w >> 1, half = w & 1;
    int hcol = j * 32 + half * 16 + (lane & 15);
    int G = gate * H_ + hcol;
    int k0 = kk * 32 + (lane >> 4) * 8;
    const float* src = (k0 < H_) ? (w_ih1 + G * H_ + k0) : (w_hh1 + G * H_ + (k0 - H_));
    f16x8 v;
    #pragma unroll
    for (int i = 0; i < 8; ++i) v[i] = (f16)src[i];
    *(f16x8*)(wsh + 262144 + t * 8) = v;
  } else if (idx < 32768 + 65536 + 4096) {            // BP (W_out), kk = w
    int t = idx - (32768 + 65536);
    int j = t >> 9, w = (t >> 6) & 7, lane = t & 63;
    int vcol = j * 16 + (lane & 15);
    int k0 = w * 32 + (lane >> 4) * 8;
    f16x8 v;
    #pragma unroll
    for (int i = 0; i < 8; ++i) v[i] = (f16)W_out[vcol * H_ + k0 + i];
    *(f16x8*)(wsh + 786432 + t * 8) = v;
  } else if (idx < 32768 + 65536 + 4096 + 131584) {   // zero H0X/H1X/CNT (1052672 B)
    int z = idx - (32768 + 65536 + 4096);
    ((u64*)((char*)ws + OFF_H0X))[z] = 0ull;
  }
}

// A-frag read from swizzled LDS h tile [16][256] f16 (row stride 512 B).
__device__ __forceinline__ f16x8 ldsA(const f16* buf, int lane, int kk) {
  int row  = lane & 15;
  int byte = row * 512 + kk * 64 + ((lane >> 4) << 4);
  byte ^= (row & 7) << 4;
  return *(const f16x8*)((const char*)buf + byte);
}

__device__ __forceinline__ u64 aload64(const u64* p) {
  return __hip_atomic_load((u64*)p, __ATOMIC_RELAXED, __HIP_MEMORY_SCOPE_AGENT);
}
__device__ __forceinline__ void astore32(unsigned* p, unsigned v) {
  __hip_atomic_store(p, v, __ATOMIC_RELAXED, __HIP_MEMORY_SCOPE_AGENT);
}
__device__ __forceinline__ void spinwait_acq(unsigned* p, unsigned target) {
  while (__hip_atomic_load(p, __ATOMIC_ACQUIRE, __HIP_MEMORY_SCOPE_AGENT) < target)
    __builtin_amdgcn_s_sleep(2);
}

// stage 4 fp32 h values (chunk c of [16][256]) -> hi/lo f16 into swizzled LDS
__device__ __forceinline__ void stage_pair(f16* bh, f16* bl, const u64* ex, int c) {
  u64 w0 = aload64(ex + 2 * c);
  u64 w1 = aload64(ex + 2 * c + 1);
  union { unsigned u; float f; } q;
  float f0, f1, f2, f3;
  q.u = (unsigned)w0;         f0 = q.f;
  q.u = (unsigned)(w0 >> 32); f1 = q.f;
  q.u = (unsigned)w1;         f2 = q.f;
  q.u = (unsigned)(w1 >> 32); f3 = q.f;
  union { f16 h[4]; u64 v; } ph, pl;
  ph.h[0] = (f16)f0; ph.h[1] = (f16)f1; ph.h[2] = (f16)f2; ph.h[3] = (f16)f3;
  pl.h[0] = (f16)(f0 - (float)ph.h[0]);
  pl.h[1] = (f16)(f1 - (float)ph.h[1]);
  pl.h[2] = (f16)(f2 - (float)ph.h[2]);
  pl.h[3] = (f16)(f3 - (float)ph.h[3]);
  int row  = c >> 6;
  int byte = row * 512 + (c & 63) * 8;
  byte ^= (row & 7) << 4;
  *(u64*)((char*)bh + byte) = ph.v;
  *(u64*)((char*)bl + byte) = pl.v;
}

__global__ __launch_bounds__(512, 2) void lstm_ws(const int* __restrict__ x,
                                                  void* __restrict__ ws,
                                                  const float* __restrict__ w_ih0,
                                                  const float* __restrict__ b_ih0,
                                                  const float* __restrict__ b_hh0,
                                                  const float* __restrict__ b_ih1,
                                                  const float* __restrict__ b_hh1,
                                                  const float* __restrict__ b_out,
                                                  float* __restrict__ out) {
  __shared__ __align__(16) f16 bufH0h[16 * 256];      // 8 KB each, swizzled
  __shared__ __align__(16) f16 bufH0l[16 * 256];
  __shared__ __align__(16) f16 bufH1h[16 * 256];
  __shared__ __align__(16) f16 bufH1l[16 * 256];
  __shared__ __align__(16) float gsc[4][16][33];      // gate scratch (padded)
  __shared__ __align__(16) float ppart[4][8][64];     // proj partials [reg][w][lane]

  const int tid  = threadIdx.x;
  const int lane = tid & 63;
  const int w    = tid >> 6;            // wave 0..7: gate = w>>1, half = w&1
  const int grp  = blockIdx.x >> 3;     // batch group 0..31 (16 rows)
  const int j    = blockIdx.x & 7;      // col block 0..7 (32 h-cols)

  // ---- persistent weight fragments in VGPRs (~100 VGPR) ----
  const f16* WB = (const f16*)ws;
  f16x8 B0r[8], B1r[16], BPr;
  {
    const f16* p0 = WB + (size_t)(j * 8 + w) * 8 * 512 + lane * 8;
    #pragma unroll
    for (int kk = 0; kk < 8; ++kk) B0r[kk] = *(const f16x8*)(p0 + kk * 512);
    const f16* p1 = WB + 262144 + (size_t)(j * 8 + w) * 16 * 512 + lane * 8;
    #pragma unroll
    for (int kk = 0; kk < 16; ++kk) B1r[kk] = *(const f16x8*)(p1 + kk * 512);
    BPr = *(const f16x8*)(WB + 786432 + (size_t)(j * 8 + w) * 512 + lane * 8);
  }

  // ---- per-thread epilogue constants: thread -> (erow = tid>>5, ecol = tid&31)
  const int erow = tid >> 5, ecol = tid & 31;
  const int hcol = j * 32 + ecol;
  const int browg = grp * 16 + erow;
  float wxv[4], bz0v[4], bz1v[4];
  #pragma unroll
  for (int g = 0; g < 4; ++g) {
    int G = g * H_ + hcol;
    wxv[g]  = w_ih0[G];
    bz0v[g] = b_ih0[G] + b_hh0[G];
    bz1v[g] = b_ih1[G] + b_hh1[G];
  }
  const float bo = (tid < 256) ? b_out[j * 16 + (tid & 15)] : 0.f;

  // exchange pointers (fp32 h)
  const u64* exH0 = (const u64*)((const char*)ws + OFF_H0X) + (size_t)grp * 2048;
  const u64* exH1 = (const u64*)((const char*)ws + OFF_H1X) + (size_t)grp * 2048;
  unsigned* exH0w = (unsigned*)((char*)ws + OFF_H0X) + (size_t)grp * 4096;
  unsigned* exH1w = (unsigned*)((char*)ws + OFF_H1X) + (size_t)grp * 4096;
  unsigned* cnt0  = (unsigned*)((char*)ws + OFF_CNT) + grp * 32;
  unsigned* cnt1  = cnt0 + 16;          // 64 B apart

  float c0 = 0.f, c1 = 0.f;

  // zero bufH0 hi/lo (h0_{-1} = 0); bufH1 staged from zeroed exchange at t=0
  ((u64*)bufH0h)[tid] = 0ull; ((u64*)bufH0h)[tid + 512] = 0ull;
  ((u64*)bufH0l)[tid] = 0ull; ((u64*)bufH0l)[tid + 512] = 0ull;
  __syncthreads();

  #pragma unroll 1
  for (int t = 0; t < S_; ++t) {
    // (1) wait for h1_{t-1}
    if (tid == 0) spinwait_acq(cnt1, (unsigned)(t * 8));
    __syncthreads();
    // (2) stage bufH1 hi/lo
    stage_pair(bufH1h, bufH1l, exH1, tid);
    stage_pair(bufH1h, bufH1l, exH1, tid + 512);
    __syncthreads();

    // (3) MFMAs not needing h0_t: layer0 (bufH0 = h0_{t-1}) -> gsc;
    //     layer1 K256-511 (bufH1) -> acc1 regs; proj (bufH1) -> ppart.
    f32x4 acc1 = {0.f, 0.f, 0.f, 0.f};
    {
      f32x4 a0 = {0.f, 0.f, 0.f, 0.f};
      #pragma unroll
      for (int kk = 0; kk < 8; ++kk) {
        a0 = __builtin_amdgcn_mfma_f32_16x16x32_f16(ldsA(bufH0h, lane, kk), B0r[kk], a0, 0, 0, 0);
        a0 = __builtin_amdgcn_mfma_f32_16x16x32_f16(ldsA(bufH0l, lane, kk), B0r[kk], a0, 0, 0, 0);
      }
      const int gate = w >> 1, half = w & 1;
      const int c16 = lane & 15, r0 = (lane >> 4) * 4;
      #pragma unroll
      for (int r = 0; r < 4; ++r) gsc[gate][r0 + r][half * 16 + c16] = a0[r];

      #pragma unroll
      for (int kk = 8; kk < 16; ++kk) {
        acc1 = __builtin_amdgcn_mfma_f32_16x16x32_f16(ldsA(bufH1h, lane, kk - 8), B1r[kk], acc1, 0, 0, 0);
        acc1 = __builtin_amdgcn_mfma_f32_16x16x32_f16(ldsA(bufH1l, lane, kk - 8), B1r[kk], acc1, 0, 0, 0);
      }
      if (t) {
        f32x4 ap = {0.f, 0.f, 0.f, 0.f};
        ap = __builtin_amdgcn_mfma_f32_16x16x32_f16(ldsA(bufH1h, lane, w), BPr, ap, 0, 0, 0);
        ap = __builtin_amdgcn_mfma_f32_16x16x32_f16(ldsA(bufH1l, lane, w), BPr, ap, 0, 0, 0);
        #pragma unroll
        for (int r = 0; r < 4; ++r) ppart[r][w][lane] = ap[r];
      }
    }
    __syncthreads();

    // (4) epilogue0: c0/h0 update, publish h0 (fp32); proj reduce -> out[t-1]
    {
      float xf = (float)x[t * B_ + browg];
      float gi = gsc[0][erow][ecol] + xf * wxv[0] + bz0v[0];
      float gf = gsc[1][erow][ecol] + xf * wxv[1] + bz0v[1];
      float gg = gsc[2][erow][ecol] + xf * wxv[2] + bz0v[2];
      float go = gsc[3][erow][ecol] + xf * wxv[3] + bz0v[3];
      c0 = sigm(gf) * c0 + sigm(gi) * tanh_fast(gg);
      float h0 = sigm(go) * tanh_fast(c0);
      union { float f; unsigned u; } hb; hb.f = h0;
      astore32(exH0w + erow * 256 + j * 32 + ecol, hb.u);
      if (t && tid < 256) {
        int prow = tid >> 4, pvc = tid & 15;
        int plane = (prow >> 2) * 16 + pvc, preg = prow & 3;
        float s = bo;
        #pragma unroll
        for (int ww = 0; ww < 8; ++ww) s += ppart[preg][ww][plane];
        out[((size_t)((t - 1) * B_ + grp * 16 + prow)) * V_ + j * 16 + pvc] = s;
      }
    }
    asm volatile("s_waitcnt vmcnt(0)" ::: "memory");   // per-wave store drain
    __syncthreads();

    // (5) bump cnt0 (RELEASE), wait all 8 col-blocks
    if (tid == 0) {
      __hip_atomic_fetch_add(cnt0, 1u, __ATOMIC_RELEASE, __HIP_MEMORY_SCOPE_AGENT);
      spinwait_acq(cnt0, (unsigned)((t + 1) * 8));
    }
    __syncthreads();
    // (6) stage bufH0 hi/lo = h0_t
    stage_pair(bufH0h, bufH0l, exH0, tid);
    stage_pair(bufH0h, bufH0l, exH0, tid + 512);
    __syncthreads();

    // (7) layer1 K0-255 (A = h0_t), continue acc1 -> gsc
    {
      #pragma unroll
      for (int kk = 0; kk < 8; ++kk) {
        acc1 = __builtin_amdgcn_mfma_f32_16x16x32_f16(ldsA(bufH0h, lane, kk), B1r[kk], acc1, 0, 0, 0);
        acc1 = __builtin_amdgcn_mfma_f32_16x16x32_f16(ldsA(bufH0l, lane, kk), B1r[kk], acc1, 0, 0, 0);
      }
      const int gate = w >> 1, half = w & 1;
      const int c16 = lane & 15, r0 = (lane >> 4) * 4;
      #pragma unroll
      for (int r = 0; r < 4; ++r) gsc[gate][r0 + r][half * 16 + c16] = acc1[r];
    }
    __syncthreads();

    // (8) epilogue1: c1/h1 update, publish h1 (fp32)
    {
      float gi = gsc[0][erow][ecol] + bz1v[0];
      float gf = gsc[1][erow][ecol] + bz1v[1];
      float gg = gsc[2][erow][ecol] + bz1v[2];
      float go = gsc[3][erow][ecol] + bz1v[3];
      c1 = sigm(gf) * c1 + sigm(gi) * tanh_fast(gg);
      float h1 = sigm(go) * tanh_fast(c1);
      union { float f; unsigned u; } hb; hb.f = h1;
      astore32(exH1w + erow * 256 + j * 32 + ecol, hb.u);
    }
    asm volatile("s_waitcnt vmcnt(0)" ::: "memory");   // per-wave store drain
    __syncthreads();

    // (9) bump cnt1 (RELEASE); next iteration's (1) waits on it
    if (tid == 0)
      __hip_atomic_fetch_add(cnt1, 1u, __ATOMIC_RELEASE, __HIP_MEMORY_SCOPE_AGENT);
  }

  // ---- tail: projection for t = S-1 ----
  if (tid == 0) spinwait_acq(cnt1, (unsigned)(S_ * 8));
  __syncthreads();
  stage_pair(bufH1h, bufH1l, exH1, tid);
  stage_pair(bufH1h, bufH1l, exH1, tid + 512);
  __syncthreads();
  {
    f32x4 ap = {0.f, 0.f, 0.f, 0.f};
    ap = __builtin_amdgcn_mfma_f32_16x16x32_f16(ldsA(bufH1h, lane, w), BPr, ap, 0, 0, 0);
    ap = __builtin_amdgcn_mfma_f32_16x16x32_f16(ldsA(bufH1l, lane, w), BPr, ap, 0, 0, 0);
    #pragma unroll
    for (int r = 0; r < 4; ++r) ppart[r][w][lane] = ap[r];
  }
  __syncthreads();
  if (tid < 256) {
    int prow = tid >> 4, pvc = tid & 15;
    int plane = (prow >> 2) * 16 + pvc, preg = prow & 3;
    float s = bo;
    #pragma unroll
    for (int ww = 0; ww < 8; ++ww) s += ppart[preg][ww][plane];
    out[((size_t)((S_ - 1) * B_ + grp * 16 + prow)) * V_ + j * 16 + pvc] = s;
  }
}

extern "C" void kernel_launch(void* const* d_in, const int* in_sizes, int n_in,
                              void* d_out, int out_size, void* d_ws, size_t ws_size,
                              hipStream_t stream) {
  const int*   x     = (const int*)d_in[0];
  const float* w_ih0 = (const float*)d_in[1];
  const float* w_hh0 = (const float*)d_in[2];
  const float* b_ih0 = (const float*)d_in[3];
  const float* b_hh0 = (const float*)d_in[4];
  const float* w_ih1 = (const float*)d_in[5];
  const float* w_hh1 = (const float*)d_in[6];
  const float* b_ih1 = (const float*)d_in[7];
  const float* b_hh1 = (const float*)d_in[8];
  const float* W_out = (const float*)d_in[9];
  const float* b_out = (const float*)d_in[10];

  // prep threads: 32768 + 65536 + 4096 + 131584 = 233984 = 914 * 256
  prep_kernel<<<914, 256, 0, stream>>>(w_hh0, w_ih1, w_hh1, W_out, d_ws);
  lstm_ws<<<256, 512, 0, stream>>>(x, d_ws, w_ih0, b_ih0, b_hh0, b_ih1, b_hh1,
                                   b_out, (float*)d_out);
}

// Round 5
// 5177.599 us; speedup vs baseline: 5.3974x; 1.4970x over previous
//
#include <hip/hip_runtime.h>

// ---------------------------------------------------------------------------
// 2-layer LSTM LM, S=512 B=512 H=256 V=128 — Round 5: weight-stationary +
// skewed single-sync pipeline.
// 256 blocks = 32 batch-groups x 8 col-blocks. Iter t computes: layer0 step t
// (reads h0_{t-1}), layer1 step t-1 (reads SAME h0_{t-1} + h1_{t-2}),
// projection step t-2. One gather + one publish + ONE tag per iter (no RMW):
// publish slices -> per-wave vmcnt(0) -> barrier -> tag store; readers
// ACQUIRE-poll the 8 peer tags. Exchange double-buffered by t&1.
// Weights pinned in VGPRs via asm keep-alive ("+v") so they are NOT
// re-fetched per step. LDS h-buffers in MFMA fragment layout [kk][lane][16B]
// -> lane-linear stage writes and conflict-free ds_read_b128 A-frag reads.
// h precision: fp16 hi/lo split (~fp32); c fp32 in regs; fp16 weights.
// ---------------------------------------------------------------------------

#define S_ 512
#define B_ 512
#define H_ 256
#define V_ 128

typedef _Float16 f16;
typedef __attribute__((ext_vector_type(8))) _Float16 f16x8;
typedef __attribute__((ext_vector_type(4))) float f32x4;
typedef unsigned long long u64;

// ws BYTE offsets
#define OFF_B0   0          // f16 frags [j8][w8][kk8][64][8]  = 512 KB (w_hh0)
#define OFF_B1   524288     // f16 frags [j8][w8][kk16][64][8] = 1 MB  (w_ih1|w_hh1)
#define OFF_BP   1572864    // f16 frags [j8][w8][64][8]       = 64 KB (W_out)
#define OFF_EX   1638400    // [g32][slot2][layer2][16][256] f32 = 2 MB
#define EX_G     65536
#define EX_SLOT  32768
#define EX_L1    16384
#define OFF_TAG  3735552    // [g32*8][16] u32 (one tag per 64 B)

__device__ __forceinline__ float sigm(float z) { return 1.0f / (1.0f + __expf(-z)); }
__device__ __forceinline__ float tanh_fast(float z) {
  return 2.0f / (1.0f + __expf(-2.0f * z)) - 1.0f;
}

__device__ __forceinline__ u64 aload64(const u64* p) {
  return __hip_atomic_load((u64*)p, __ATOMIC_RELAXED, __HIP_MEMORY_SCOPE_AGENT);
}
__device__ __forceinline__ void astore32(unsigned* p, unsigned v) {
  __hip_atomic_store(p, v, __ATOMIC_RELAXED, __HIP_MEMORY_SCOPE_AGENT);
}

// ---------------------------------------------------------------------------
// prep: pack weights into per-(block,wave) fp16 MFMA B-fragment streams;
// zero the 256 tags. B frag (16x16x32): lane l elem i -> B[k][n],
// k = kk*32+(l>>4)*8+i, n = l&15. Wave w of col-block j: gate=w>>1, half=w&1,
// hcol = j*32 + half*16 + n.
// ---------------------------------------------------------------------------
__global__ void prep_kernel(const float* __restrict__ w_hh0,
                            const float* __restrict__ w_ih1, const float* __restrict__ w_hh1,
                            const float* __restrict__ W_out, void* __restrict__ ws) {
  int idx = blockIdx.x * blockDim.x + threadIdx.x;
  f16* wsh = (f16*)ws;
  if (idx < 32768) {                                  // B0 (w_hh0)
    int j = idx >> 12, w = (idx >> 9) & 7, kk = (idx >> 6) & 7, lane = idx & 63;
    int gate = w >> 1, half = w & 1;
    int hcol = j * 32 + half * 16 + (lane & 15);
    int G = gate * H_ + hcol;
    int k0 = kk * 32 + (lane >> 4) * 8;
    f16x8 v;
    #pragma unroll
    for (int i = 0; i < 8; ++i) v[i] = (f16)w_hh0[G * H_ + k0 + i];
    *(f16x8*)(wsh + idx * 8) = v;
  } else if (idx < 32768 + 65536) {                   // B1 (K=512: w_ih1 | w_hh1)
    int t = idx - 32768;
    int j = t >> 13, w = (t >> 10) & 7, kk = (t >> 6) & 15, lane = t & 63;
    int gate = w >> 1, half = w & 1;
    int hcol = j * 32 + half * 16 + (lane & 15);
    int G = gate * H_ + hcol;
    int k0 = kk * 32 + (lane >> 4) * 8;
    const float* src = (k0 < H_) ? (w_ih1 + G * H_ + k0) : (w_hh1 + G * H_ + (k0 - H_));
    f16x8 v;
    #pragma unroll
    for (int i = 0; i < 8; ++i) v[i] = (f16)src[i];
    *(f16x8*)(wsh + 262144 + t * 8) = v;
  } else if (idx < 32768 + 65536 + 4096) {            // BP (W_out), kk = w (K-split)
    int t = idx - (32768 + 65536);
    int j = t >> 9, w = (t >> 6) & 7, lane = t & 63;
    int vcol = j * 16 + (lane & 15);
    int k0 = w * 32 + (lane >> 4) * 8;
    f16x8 v;
    #pragma unroll
    for (int i = 0; i < 8; ++i) v[i] = (f16)W_out[vcol * H_ + k0 + i];
    *(f16x8*)(wsh + 786432 + t * 8) = v;
  } else if (idx < 32768 + 65536 + 4096 + 4096) {     // zero tags (16 KB)
    int t = idx - (32768 + 65536 + 4096);
    ((unsigned*)((char*)ws + OFF_TAG))[t] = 0u;
  }
}

// stage 8 fp32 h values -> hi/lo f16 frag word at LDS [tid*16B] (lane-linear)
__device__ __forceinline__ void stage8(f16* bh, f16* bl, const float* src, int tid) {
  u64 q[4];
  #pragma unroll
  for (int i = 0; i < 4; ++i) q[i] = aload64((const u64*)src + i);
  union { f16 h[8]; u64 v[2]; } Hh, Ll;
  #pragma unroll
  for (int i = 0; i < 4; ++i) {
    union { unsigned u; float f; } a, b;
    a.u = (unsigned)q[i]; b.u = (unsigned)(q[i] >> 32);
    f16 h0 = (f16)a.f; Hh.h[2 * i]     = h0; Ll.h[2 * i]     = (f16)(a.f - (float)h0);
    f16 h1 = (f16)b.f; Hh.h[2 * i + 1] = h1; Ll.h[2 * i + 1] = (f16)(b.f - (float)h1);
  }
  ((u64*)bh)[tid * 2]     = Hh.v[0];
  ((u64*)bh)[tid * 2 + 1] = Hh.v[1];
  ((u64*)bl)[tid * 2]     = Ll.v[0];
  ((u64*)bl)[tid * 2 + 1] = Ll.v[1];
}

// A-frag read, fragment-layout LDS: conflict-free (lane-consecutive 16B)
__device__ __forceinline__ f16x8 afrag(const f16* buf, int lane, int kk) {
  return *(const f16x8*)(buf + kk * 512 + lane * 8);
}

__global__ __launch_bounds__(512, 2) void lstm_skew(const int* __restrict__ x,
                                                    void* __restrict__ ws,
                                                    const float* __restrict__ w_ih0,
                                                    const float* __restrict__ b_ih0,
                                                    const float* __restrict__ b_hh0,
                                                    const float* __restrict__ b_ih1,
                                                    const float* __restrict__ b_hh1,
                                                    const float* __restrict__ b_out,
                                                    float* __restrict__ out) {
  __shared__ __align__(16) f16 H0h[4096], H0l[4096], H1h[4096], H1l[4096]; // 32 KB
  __shared__ __align__(16) float gsc0[4][16][33];     // layer0 gate scratch
  __shared__ __align__(16) float gsc1[4][16][33];     // layer1 gate scratch
  __shared__ __align__(16) float ppart[4][8][64];     // proj K-split partials

  const int tid  = threadIdx.x;
  const int lane = tid & 63;
  const int w    = tid >> 6;            // wave 0..7: gate = w>>1, half = w&1
  const int grp  = blockIdx.x >> 3;     // batch group 0..31 (16 rows)
  const int j    = blockIdx.x & 7;      // col block 0..7 (32 h-cols)

  // ---- persistent weight fragments, pinned in VGPRs ----
  const f16* WB = (const f16*)ws;
  f16x8 B0r[8], B1r[16], BPr;
  {
    const f16* p0 = WB + (size_t)(j * 8 + w) * 8 * 512 + lane * 8;
    #pragma unroll
    for (int kk = 0; kk < 8; ++kk) B0r[kk] = *(const f16x8*)(p0 + kk * 512);
    const f16* p1 = WB + 262144 + (size_t)(j * 8 + w) * 16 * 512 + lane * 8;
    #pragma unroll
    for (int kk = 0; kk < 16; ++kk) B1r[kk] = *(const f16x8*)(p1 + kk * 512);
    BPr = *(const f16x8*)(WB + 786432 + (size_t)(j * 8 + w) * 512 + lane * 8);
    // keep-alive: prevent the compiler from re-loading these per iteration
    #pragma unroll
    for (int kk = 0; kk < 8; ++kk) asm volatile("" : "+v"(B0r[kk]));
    #pragma unroll
    for (int kk = 0; kk < 16; ++kk) asm volatile("" : "+v"(B1r[kk]));
    asm volatile("" : "+v"(BPr));
  }

  // ---- per-thread epilogue constants: (erow = tid>>5, ecol = tid&31) ----
  const int erow = tid >> 5, ecol = tid & 31;
  const int hcol = j * 32 + ecol;
  const int browg = grp * 16 + erow;
  float wxv[4], bz0v[4], bz1v[4];
  #pragma unroll
  for (int g = 0; g < 4; ++g) {
    int G = g * H_ + hcol;
    wxv[g]  = w_ih0[G];
    bz0v[g] = b_ih0[G] + b_hh0[G];
    bz1v[g] = b_ih1[G] + b_hh1[G];
  }
  const float bo = (tid < 256) ? b_out[j * 16 + (tid & 15)] : 0.f;

  char* exG = (char*)ws + OFF_EX + (size_t)grp * EX_G;
  unsigned* tagBase = (unsigned*)((char*)ws + OFF_TAG);
  unsigned* myTag = tagBase + (grp * 8 + j) * 16;

  // staging source indices for this thread's frag word
  const int skk = tid >> 6, sln = tid & 63;
  const int srow = sln & 15, sk0 = skk * 32 + ((sln >> 4) << 3);

  float c0 = 0.f, c1 = 0.f;

  // zero LDS h buffers (h0_{-1} = h1_{-2} = 0)
  #pragma unroll
  for (int i = 0; i < 2; ++i) {
    ((u64*)H0h)[tid + i * 512] = 0ull; ((u64*)H0l)[tid + i * 512] = 0ull;
    ((u64*)H1h)[tid + i * 512] = 0ull; ((u64*)H1l)[tid + i * 512] = 0ull;
  }
  __syncthreads();

  #pragma unroll 1
  for (int t = 0; t <= S_ + 1; ++t) {
    // ---- (1) wait for all 8 peers to finish iter t-1; gather slot[(t-1)&1]
    if (t > 0) {
      if (w == 0) {
        const unsigned tgt = (unsigned)t;
        for (;;) {
          unsigned v = tgt;
          if (lane < 8)
            v = __hip_atomic_load(tagBase + (grp * 8 + lane) * 16,
                                  __ATOMIC_ACQUIRE, __HIP_MEMORY_SCOPE_AGENT);
          if (__all((int)(v >= tgt))) break;
          __builtin_amdgcn_s_sleep(1);
        }
      }
      __syncthreads();
      const char* slot = exG + ((t - 1) & 1) * EX_SLOT;
      stage8(H1h, H1l, (const float*)(slot + EX_L1) + srow * 256 + sk0, tid);
      if (t <= S_)
        stage8(H0h, H0l, (const float*)slot + srow * 256 + sk0, tid);
      __syncthreads();
    }

    // ---- (2) MFMA: layer0(t), layer1(t-1), proj(t-2) — shared A-frag reads
    {
      f32x4 acc0 = {0.f, 0.f, 0.f, 0.f};
      f32x4 acc1 = {0.f, 0.f, 0.f, 0.f};
      f32x4 ap   = {0.f, 0.f, 0.f, 0.f};
      #pragma unroll
      for (int kk = 0; kk < 8; ++kk) {
        f16x8 ah = afrag(H0h, lane, kk), al = afrag(H0l, lane, kk);
        acc0 = __builtin_amdgcn_mfma_f32_16x16x32_f16(ah, B0r[kk], acc0, 0, 0, 0);
        acc0 = __builtin_amdgcn_mfma_f32_16x16x32_f16(al, B0r[kk], acc0, 0, 0, 0);
        acc1 = __builtin_amdgcn_mfma_f32_16x16x32_f16(ah, B1r[kk], acc1, 0, 0, 0);
        acc1 = __builtin_amdgcn_mfma_f32_16x16x32_f16(al, B1r[kk], acc1, 0, 0, 0);
      }
      #pragma unroll
      for (int kk = 0; kk < 8; ++kk) {
        f16x8 ah = afrag(H1h, lane, kk), al = afrag(H1l, lane, kk);
        acc1 = __builtin_amdgcn_mfma_f32_16x16x32_f16(ah, B1r[kk + 8], acc1, 0, 0, 0);
        acc1 = __builtin_amdgcn_mfma_f32_16x16x32_f16(al, B1r[kk + 8], acc1, 0, 0, 0);
      }
      {
        f16x8 ah = afrag(H1h, lane, w), al = afrag(H1l, lane, w);
        ap = __builtin_amdgcn_mfma_f32_16x16x32_f16(ah, BPr, ap, 0, 0, 0);
        ap = __builtin_amdgcn_mfma_f32_16x16x32_f16(al, BPr, ap, 0, 0, 0);
      }
      const int gate = w >> 1, half = w & 1;
      const int c16 = lane & 15, r0 = (lane >> 4) * 4;
      #pragma unroll
      for (int r = 0; r < 4; ++r) {
        gsc0[gate][r0 + r][half * 16 + c16] = acc0[r];
        gsc1[gate][r0 + r][half * 16 + c16] = acc1[r];
        ppart[r][w][lane] = ap[r];
      }
    }
    __syncthreads();

    // ---- (3) epilogues + publishes into slot[t&1]
    unsigned* slotW = (unsigned*)(exG + (t & 1) * EX_SLOT);
    // layer0 step t -> h0_t
    if (t < S_) {
      float xf = (float)x[t * B_ + browg];
      float gi = gsc0[0][erow][ecol] + xf * wxv[0] + bz0v[0];
      float gf = gsc0[1][erow][ecol] + xf * wxv[1] + bz0v[1];
      float gg = gsc0[2][erow][ecol] + xf * wxv[2] + bz0v[2];
      float go = gsc0[3][erow][ecol] + xf * wxv[3] + bz0v[3];
      c0 = sigm(gf) * c0 + sigm(gi) * tanh_fast(gg);
      float h0 = sigm(go) * tanh_fast(c0);
      union { float f; unsigned u; } hb; hb.f = h0;
      astore32(slotW + erow * 256 + j * 32 + ecol, hb.u);
    }
    // layer1 step t-1 -> h1_{t-1} (zeros at t==0)
    if (t <= S_) {
      float h1 = 0.f;
      if (t >= 1) {
        float gi = gsc1[0][erow][ecol] + bz1v[0];
        float gf = gsc1[1][erow][ecol] + bz1v[1];
        float gg = gsc1[2][erow][ecol] + bz1v[2];
        float go = gsc1[3][erow][ecol] + bz1v[3];
        c1 = sigm(gf) * c1 + sigm(gi) * tanh_fast(gg);
        h1 = sigm(go) * tanh_fast(c1);
      }
      union { float f; unsigned u; } hb; hb.f = h1;
      astore32(slotW + 4096 + erow * 256 + j * 32 + ecol, hb.u);
    }
    // projection step t-2 (from h1_{t-2} staged in bufH1)
    if (t >= 2 && tid < 256) {
      int prow = tid >> 4, pvc = tid & 15;
      int plane = (prow >> 2) * 16 + pvc, preg = prow & 3;
      float s = bo;
      #pragma unroll
      for (int ww = 0; ww < 8; ++ww) s += ppart[preg][ww][plane];
      out[((size_t)((t - 2) * B_ + grp * 16 + prow)) * V_ + j * 16 + pvc] = s;
    }

    // ---- (4) drain stores, then publish tag t+1 (single store, no RMW)
    if (t <= S_) {
      asm volatile("s_waitcnt vmcnt(0)" ::: "memory");
      __syncthreads();
      if (tid == 0)
        __hip_atomic_store(myTag, (unsigned)(t + 1),
                           __ATOMIC_RELEASE, __HIP_MEMORY_SCOPE_AGENT);
    }
  }
}

extern "C" void kernel_launch(void* const* d_in, const int* in_sizes, int n_in,
                              void* d_out, int out_size, void* d_ws, size_t ws_size,
                              hipStream_t stream) {
  const int*   x     = (const int*)d_in[0];
  const float* w_ih0 = (const float*)d_in[1];
  const float* w_hh0 = (const float*)d_in[2];
  const float* b_ih0 = (const float*)d_in[3];
  const float* b_hh0 = (const float*)d_in[4];
  const float* w_ih1 = (const float*)d_in[5];
  const float* w_hh1 = (const float*)d_in[6];
  const float* b_ih1 = (const float*)d_in[7];
  const float* b_hh1 = (const float*)d_in[8];
  const float* W_out = (const float*)d_in[9];
  const float* b_out = (const float*)d_in[10];

  // prep threads: 32768 + 65536 + 4096 + 4096 = 106496 = 416 * 256
  prep_kernel<<<416, 256, 0, stream>>>(w_hh0, w_ih1, w_hh1, W_out, d_ws);
  lstm_skew<<<256, 512, 0, stream>>>(x, d_ws, w_ih0, b_ih0, b_hh0, b_ih1, b_hh1,
                                     b_out, (float*)d_out);
}

// Round 8
// 2667.590 us; speedup vs baseline: 10.4759x; 1.9409x over previous
//
#include <hip/hip_runtime.h>

// ---------------------------------------------------------------------------
// 2-layer LSTM LM, S=512 B=512 H=256 V=128 — Round 8: R5 structure (proven)
// with relaxed-only sync (no per-poll L2 invalidation), per-wave parallel
// poll+gather (wave w owns peer w == frag tile kk=w), and no in-loop
// keep-alives (weights alias-protected via __restrict__, resident in
// VGPR/AGPR). 256 blocks = 32 batch-groups x 8 col-blocks.
// Skewed schedule per iter t: L0(t) + L1(t-1) + proj(t-2); one tag/iter.
// Protocol (R5-proven): publish slices (relaxed agent stores) -> per-wave
// s_waitcnt vmcnt(0) -> barrier -> tid0 tag store. Readers: relaxed poll
// of their peer's tag, compiler barrier, relaxed gather. Slots double-
// buffered by t&1; overwrite-safe (tag>=t proves peers consumed slot t&1).
// h precision: fp16 hi/lo split (~fp32); c fp32 in regs; fp16 weights.
// ---------------------------------------------------------------------------

#define S_ 512
#define B_ 512
#define H_ 256
#define V_ 128

typedef _Float16 f16;
typedef __attribute__((ext_vector_type(8))) _Float16 f16x8;
typedef __attribute__((ext_vector_type(4))) float f32x4;
typedef unsigned long long u64;
typedef unsigned u32;

// ws BYTE offsets
#define OFF_B0   0          // f16 frags [j8][w8][kk8][64][8]  = 512 KB (w_hh0)
#define OFF_B1   524288     // f16 frags [j8][w8][kk16][64][8] = 1 MB  (w_ih1|w_hh1)
#define OFF_BP   1572864    // f16 frags [j8][w8][64][8]       = 64 KB (W_out)
#define OFF_EX   1638400    // [bg32][slot2][layer2][16][256] f32 = 2 MB
#define OFF_TAG  3735552    // [bg32][j8] u32, one per 128 B = 32 KB

__device__ __forceinline__ float sigm(float z) { return 1.0f / (1.0f + __expf(-z)); }
__device__ __forceinline__ float tanh_fast(float z) {
  return 2.0f / (1.0f + __expf(-2.0f * z)) - 1.0f;
}

// ---------------------------------------------------------------------------
// prep: pack weights into per-(colblock,wave) fp16 MFMA B-fragment streams;
// zero tags. B frag (16x16x32): lane l elem i -> B[k][n],
// k = kk*32+(l>>4)*8+i, n = l&15. Wave w of col-block j: gate=w>>1, half=w&1,
// hcol = j*32 + half*16 + n.
// ---------------------------------------------------------------------------
__global__ void prep_kernel(const float* __restrict__ w_hh0,
                            const float* __restrict__ w_ih1, const float* __restrict__ w_hh1,
                            const float* __restrict__ W_out, void* __restrict__ ws) {
  int idx = blockIdx.x * blockDim.x + threadIdx.x;
  f16* wsh = (f16*)ws;
  if (idx < 32768) {                                  // B0 (w_hh0)
    int j = idx >> 12, w = (idx >> 9) & 7, kk = (idx >> 6) & 7, lane = idx & 63;
    int gate = w >> 1, half = w & 1;
    int hcol = j * 32 + half * 16 + (lane & 15);
    int G = gate * H_ + hcol;
    int k0 = kk * 32 + (lane >> 4) * 8;
    f16x8 v;
    #pragma unroll
    for (int i = 0; i < 8; ++i) v[i] = (f16)w_hh0[G * H_ + k0 + i];
    *(f16x8*)(wsh + idx * 8) = v;
  } else if (idx < 32768 + 65536) {                   // B1 (K=512: w_ih1 | w_hh1)
    int t = idx - 32768;
    int j = t >> 13, w = (t >> 10) & 7, kk = (t >> 6) & 15, lane = t & 63;
    int gate = w >> 1, half = w & 1;
    int hcol = j * 32 + half * 16 + (lane & 15);
    int G = gate * H_ + hcol;
    int k0 = kk * 32 + (lane >> 4) * 8;
    const float* src = (k0 < H_) ? (w_ih1 + G * H_ + k0) : (w_hh1 + G * H_ + (k0 - H_));
    f16x8 v;
    #pragma unroll
    for (int i = 0; i < 8; ++i) v[i] = (f16)src[i];
    *(f16x8*)(wsh + 262144 + t * 8) = v;
  } else if (idx < 32768 + 65536 + 4096) {            // BP (W_out), kk = w
    int t = idx - (32768 + 65536);
    int j = t >> 9, w = (t >> 6) & 7, lane = t & 63;
    int vcol = j * 16 + (lane & 15);
    int k0 = w * 32 + (lane >> 4) * 8;
    f16x8 v;
    #pragma unroll
    for (int i = 0; i < 8; ++i) v[i] = (f16)W_out[vcol * H_ + k0 + i];
    *(f16x8*)(wsh + 786432 + t * 8) = v;
  } else if (idx < 110592) {                          // zero tags (32 KB)
    ((u32*)((char*)ws + OFF_TAG))[idx - 102400] = 0u;
  }
}

__device__ __forceinline__ u64 aload64(const u64* p) {
  return __hip_atomic_load((u64*)p, __ATOMIC_RELAXED, __HIP_MEMORY_SCOPE_AGENT);
}
__device__ __forceinline__ u32 aload32(const u32* p) {
  return __hip_atomic_load((u32*)p, __ATOMIC_RELAXED, __HIP_MEMORY_SCOPE_AGENT);
}
__device__ __forceinline__ void astore32(u32* p, u32 v) {
  __hip_atomic_store(p, v, __ATOMIC_RELAXED, __HIP_MEMORY_SCOPE_AGENT);
}
// 8 consecutive fp32 via relaxed agent loads (MALL-coherent bypass path)
__device__ __forceinline__ void agather8(const float* p, f32x4& a, f32x4& b) {
  u64 q0 = aload64((const u64*)p),     q1 = aload64((const u64*)p + 1);
  u64 q2 = aload64((const u64*)p + 2), q3 = aload64((const u64*)p + 3);
  union { u32 u; float f; } c;
  c.u = (u32)q0; a[0] = c.f; c.u = (u32)(q0 >> 32); a[1] = c.f;
  c.u = (u32)q1; a[2] = c.f; c.u = (u32)(q1 >> 32); a[3] = c.f;
  c.u = (u32)q2; b[0] = c.f; c.u = (u32)(q2 >> 32); b[1] = c.f;
  c.u = (u32)q3; b[2] = c.f; c.u = (u32)(q3 >> 32); b[3] = c.f;
}

// convert 8 fp32 -> hi/lo f16 and store into frag-layout LDS at tid*16B
__device__ __forceinline__ void cvt8(f32x4 a, f32x4 b, f16* bh, f16* bl, int tid) {
  float f[8] = {a[0], a[1], a[2], a[3], b[0], b[1], b[2], b[3]};
  union { f16 h[8]; u64 v[2]; } Hh, Ll;
  #pragma unroll
  for (int i = 0; i < 8; ++i) {
    f16 hi = (f16)f[i];
    Hh.h[i] = hi;
    Ll.h[i] = (f16)(f[i] - (float)hi);
  }
  ((u64*)bh)[tid * 2]     = Hh.v[0];
  ((u64*)bh)[tid * 2 + 1] = Hh.v[1];
  ((u64*)bl)[tid * 2]     = Ll.v[0];
  ((u64*)bl)[tid * 2 + 1] = Ll.v[1];
}

// A-frag read, fragment-layout LDS: conflict-free (lane-consecutive 16B)
__device__ __forceinline__ f16x8 afrag(const f16* buf, int lane, int kk) {
  return *(const f16x8*)(buf + kk * 512 + lane * 8);
}

__global__ __launch_bounds__(512, 2) void lstm_r8(const int* __restrict__ x,
                                                  const f16* __restrict__ wts,
                                                  char* __restrict__ ex,
                                                  u32* __restrict__ tags,
                                                  const float* __restrict__ w_ih0,
                                                  const float* __restrict__ b_ih0,
                                                  const float* __restrict__ b_hh0,
                                                  const float* __restrict__ b_ih1,
                                                  const float* __restrict__ b_hh1,
                                                  const float* __restrict__ b_out,
                                                  float* __restrict__ out) {
  __shared__ __align__(16) f16 H0h[4096], H0l[4096], H1h[4096], H1l[4096]; // 32 KB
  __shared__ __align__(16) float gsc0[4][16][33];
  __shared__ __align__(16) float gsc1[4][16][33];
  __shared__ __align__(16) float ppart[4][8][64];

  const int tid  = threadIdx.x;
  const int lane = tid & 63;
  const int w    = tid >> 6;            // wave 0..7: gate = w>>1, half = w&1
  const int bg   = blockIdx.x >> 3;     // batch group 0..31 (16 rows)
  const int j    = blockIdx.x & 7;      // col block 0..7 (32 h-cols)

  // ---- persistent weight fragments (VGPR/AGPR resident; wts is __restrict__
  //      and never stored through, so no per-iter reloads) ----
  f16x8 B0r[8], B1r[16], BPr;
  {
    const f16* p0 = wts + (size_t)(j * 8 + w) * 8 * 512 + lane * 8;
    #pragma unroll
    for (int kk = 0; kk < 8; ++kk) B0r[kk] = *(const f16x8*)(p0 + kk * 512);
    const f16* p1 = wts + 262144 + (size_t)(j * 8 + w) * 16 * 512 + lane * 8;
    #pragma unroll
    for (int kk = 0; kk < 16; ++kk) B1r[kk] = *(const f16x8*)(p1 + kk * 512);
    BPr = *(const f16x8*)(wts + 786432 + (size_t)(j * 8 + w) * 512 + lane * 8);
  }

  // ---- per-thread epilogue constants: (erow = tid>>5, ecol = tid&31) ----
  const int erow = tid >> 5, ecol = tid & 31;
  const int hcol = j * 32 + ecol;
  const int browg = bg * 16 + erow;
  float wxv[4], bz0v[4], bz1v[4];
  #pragma unroll
  for (int g = 0; g < 4; ++g) {
    int G = g * H_ + hcol;
    wxv[g]  = w_ih0[G];
    bz0v[g] = b_ih0[G] + b_hh0[G];
    bz1v[g] = b_ih1[G] + b_hh1[G];
  }
  const float bo = (tid < 256) ? b_out[j * 16 + (tid & 15)] : 0.f;

  char* exG = ex + (size_t)bg * 65536;
  u32* tagB = tags + (size_t)bg * 8 * 32;             // 128 B apart
  u32* myTag = tagB + j * 32;
  u32* peerTag = tagB + w * 32;                       // wave w owns peer w

  // gather indexing: wave w == peer w == frag tile kk=w
  const int grow = lane & 15;
  const int gcol = w * 32 + ((lane >> 4) << 3);

  float c0 = 0.f, c1 = 0.f;

  // zero LDS h buffers (h0_{-1} = h1_{-1} = 0)
  #pragma unroll
  for (int i = 0; i < 2; ++i) {
    ((u64*)H0h)[tid + i * 512] = 0ull; ((u64*)H0l)[tid + i * 512] = 0ull;
    ((u64*)H1h)[tid + i * 512] = 0ull; ((u64*)H1l)[tid + i * 512] = 0ull;
  }
  __syncthreads();

  #pragma unroll 1
  for (int t = 0; t <= S_ + 1; ++t) {
    // x for this thread's row (issued before poll -> overlaps sync latency)
    float xf = (t < S_) ? (float)x[t * B_ + browg] : 0.f;

    // ---- (1) per-wave relaxed poll of peer w, then gather tile kk=w ----
    if (t > 0) {
      const u32 need = (u32)t;
      while (aload32(peerTag) < need) __builtin_amdgcn_s_sleep(1);
      asm volatile("" ::: "memory");    // compiler barrier: no hoist/sink
      const float* slotR = (const float*)(exG + ((t - 1) & 1) * 32768);
      f32x4 a0, a1, d0, d1;
      agather8(slotR + grow * 256 + gcol, a0, a1);          // h0_{t-1}
      agather8(slotR + 4096 + grow * 256 + gcol, d0, d1);   // h1_{t-2}
      cvt8(a0, a1, H0h, H0l, tid);
      cvt8(d0, d1, H1h, H1l, tid);
    }
    __syncthreads();

    // ---- (2) MFMA: L0(t), L1(t-1), proj(t-2) — shared A-frag reads ----
    {
      f32x4 acc0 = {0.f, 0.f, 0.f, 0.f};
      f32x4 acc1 = {0.f, 0.f, 0.f, 0.f};
      f32x4 ap   = {0.f, 0.f, 0.f, 0.f};
      #pragma unroll
      for (int kk = 0; kk < 8; ++kk) {
        f16x8 ah = afrag(H0h, lane, kk), al = afrag(H0l, lane, kk);
        acc0 = __builtin_amdgcn_mfma_f32_16x16x32_f16(ah, B0r[kk], acc0, 0, 0, 0);
        acc0 = __builtin_amdgcn_mfma_f32_16x16x32_f16(al, B0r[kk], acc0, 0, 0, 0);
        acc1 = __builtin_amdgcn_mfma_f32_16x16x32_f16(ah, B1r[kk], acc1, 0, 0, 0);
        acc1 = __builtin_amdgcn_mfma_f32_16x16x32_f16(al, B1r[kk], acc1, 0, 0, 0);
      }
      #pragma unroll
      for (int kk = 0; kk < 8; ++kk) {
        f16x8 ah = afrag(H1h, lane, kk), al = afrag(H1l, lane, kk);
        acc1 = __builtin_amdgcn_mfma_f32_16x16x32_f16(ah, B1r[kk + 8], acc1, 0, 0, 0);
        acc1 = __builtin_amdgcn_mfma_f32_16x16x32_f16(al, B1r[kk + 8], acc1, 0, 0, 0);
      }
      {
        f16x8 ah = afrag(H1h, lane, w), al = afrag(H1l, lane, w);
        ap = __builtin_amdgcn_mfma_f32_16x16x32_f16(ah, BPr, ap, 0, 0, 0);
        ap = __builtin_amdgcn_mfma_f32_16x16x32_f16(al, BPr, ap, 0, 0, 0);
      }
      const int gate = w >> 1, half = w & 1;
      const int c16 = lane & 15, r0 = (lane >> 4) * 4;
      #pragma unroll
      for (int r = 0; r < 4; ++r) {
        gsc0[gate][r0 + r][half * 16 + c16] = acc0[r];
        gsc1[gate][r0 + r][half * 16 + c16] = acc1[r];
        ppart[r][w][lane] = ap[r];
      }
    }
    __syncthreads();

    // ---- (3) epilogues + publishes into slot[t&1] (relaxed agent stores) --
    u32* slotW = (u32*)(exG + (t & 1) * 32768);
    if (t < S_) {                         // layer0 step t -> h0_t
      float gi = gsc0[0][erow][ecol] + xf * wxv[0] + bz0v[0];
      float gf = gsc0[1][erow][ecol] + xf * wxv[1] + bz0v[1];
      float gg = gsc0[2][erow][ecol] + xf * wxv[2] + bz0v[2];
      float go = gsc0[3][erow][ecol] + xf * wxv[3] + bz0v[3];
      c0 = sigm(gf) * c0 + sigm(gi) * tanh_fast(gg);
      float h0 = sigm(go) * tanh_fast(c0);
      union { float f; u32 u; } hb; hb.f = h0;
      astore32(slotW + erow * 256 + hcol, hb.u);
    }
    if (t <= S_) {                        // layer1 step t-1 -> h1_{t-1}
      float h1 = 0.f;
      if (t >= 1) {
        float gi = gsc1[0][erow][ecol] + bz1v[0];
        float gf = gsc1[1][erow][ecol] + bz1v[1];
        float gg = gsc1[2][erow][ecol] + bz1v[2];
        float go = gsc1[3][erow][ecol] + bz1v[3];
        c1 = sigm(gf) * c1 + sigm(gi) * tanh_fast(gg);
        h1 = sigm(go) * tanh_fast(c1);
      }
      union { float f; u32 u; } hb; hb.f = h1;
      astore32(slotW + 4096 + erow * 256 + hcol, hb.u);
    }
    if (t >= 2 && tid < 256) {            // projection step t-2 -> out
      int prow = tid >> 4, pvc = tid & 15;
      int plane = (prow >> 2) * 16 + pvc, preg = prow & 3;
      float s = bo;
      #pragma unroll
      for (int ww = 0; ww < 8; ++ww) s += ppart[preg][ww][plane];
      out[((size_t)((t - 2) * B_ + bg * 16 + prow)) * V_ + j * 16 + pvc] = s;
    }

    // ---- (4) per-wave drain, barrier, then single relaxed tag store ----
    if (t <= S_) {
      asm volatile("s_waitcnt vmcnt(0)" ::: "memory");
      __syncthreads();                    // all waves' publishes are at MALL
      if (tid == 0) astore32(myTag, (u32)(t + 1));
    }
  }
}

extern "C" void kernel_launch(void* const* d_in, const int* in_sizes, int n_in,
                              void* d_out, int out_size, void* d_ws, size_t ws_size,
                              hipStream_t stream) {
  const int*   x     = (const int*)d_in[0];
  const float* w_ih0 = (const float*)d_in[1];
  const float* w_hh0 = (const float*)d_in[2];
  const float* b_ih0 = (const float*)d_in[3];
  const float* b_hh0 = (const float*)d_in[4];
  const float* w_ih1 = (const float*)d_in[5];
  const float* w_hh1 = (const float*)d_in[6];
  const float* b_ih1 = (const float*)d_in[7];
  const float* b_hh1 = (const float*)d_in[8];
  const float* W_out = (const float*)d_in[9];
  const float* b_out = (const float*)d_in[10];

  // prep threads: 32768 + 65536 + 4096 + 8192 = 110592 = 432 * 256
  prep_kernel<<<432, 256, 0, stream>>>(w_hh0, w_ih1, w_hh1, W_out, d_ws);

  lstm_r8<<<256, 512, 0, stream>>>(x, (const f16*)d_ws,
                                   (char*)d_ws + OFF_EX, (u32*)((char*)d_ws + OFF_TAG),
                                   w_ih0, b_ih0, b_hh0, b_ih1, b_hh1, b_out,
                                   (float*)d_out);
}